// Round 5
// baseline (40.349 us; speedup 1.0000x reference)
//
#include <hip/hip_runtime.h>
#include <hip/hip_bf16.h>

#define NH 32          // heads
#define NV 1537        // edge_enc_w rows
#define ND 20          // MULTI_HOP_MAX_DIST
#define NB 16          // batch
#define NN 64          // nodes

#define TROWS (ND*NV)                    // 30740
#define TBLOCKS ((TROWS + 7) / 8)        // 3843

typedef unsigned int   u32;
typedef unsigned short u16;
typedef __attribute__((ext_vector_type(2))) unsigned int   u32x2;
typedef __attribute__((ext_vector_type(2))) float          f32x2;
typedef __attribute__((ext_vector_type(4))) int            v4i;
typedef __attribute__((ext_vector_type(4))) float          v4f;
typedef __attribute__((ext_vector_type(4))) unsigned short v4h;

__device__ __forceinline__ float asf(u32 u) { return __uint_as_float(u); }

// ---------------- Kernel 1: T[d][v][h] = sum_k enc[v][k] * Wd[d][k][h], bf16 ----------
__global__ void __launch_bounds__(256)
prep_kernel(const float* __restrict__ enc,     // (1537,32)
            const float* __restrict__ wdis,    // (20,32,32)
            __hip_bfloat16* __restrict__ T) {  // (20,1537,32) out
    int row = blockIdx.x * 8 + (threadIdx.x >> 5);
    int h   = threadIdx.x & 31;
    if (row >= TROWS) return;
    int d = row / NV, v = row - d * NV;
    const float4* e4 = (const float4*)(enc + v * NH);
    const float*  w  = wdis + d * NH * NH + h;
    float acc = 0.f;
#pragma unroll
    for (int k4 = 0; k4 < 8; ++k4) {
        float4 e = e4[k4];
        acc += e.x * w[(k4 * 4 + 0) * NH];
        acc += e.y * w[(k4 * 4 + 1) * NH];
        acc += e.z * w[(k4 * 4 + 2) * NH];
        acc += e.w * w[(k4 * 4 + 3) * NH];
    }
    T[row * NH + h] = __float2bfloat16(acc);
}

// ---------------- Kernel 2: one block per (b, out-row r), 512 threads ----------------
// r==0: token row.  r>=1: 64 interior cells (i=r-1, j=0..63) -> out cols 1..64,
// token col 0. Gather: 8 lanes/cell, lane l = head-quad, u16 pre-biased indices.
__global__ void __launch_bounds__(512, 6)
main_kernel(const float* __restrict__ ab,      // (B,65,65)
            const int*   __restrict__ spos,    // (B,64,64)
            const int*   __restrict__ eidx,    // (B,64,64,20,3)
            const float* __restrict__ mask2d,  // (B,)
            const float* __restrict__ spw,     // (512,32)
            const float* __restrict__ tokw,    // (32,)
            const u32*   __restrict__ Tw,      // T rows: 16 uints (bf16x2)
            float*       __restrict__ out) {   // (B,32,65,65)
    __shared__ u16   sidx[64 * 60];            // 7680 B, pre-biased d*NV+idx
    __shared__ float comb[NH * 65];            // 8320 B, [h][out-j]
    __shared__ float abrow[65];

    int tid = threadIdx.x;
    int blk = blockIdx.x;                      // b*65 + r
    int b = blk / 65, r = blk - b * 65;

    if (tid < 65) abrow[tid] = ab[(b * 65 + r) * 65 + tid];

    if (r > 0) {
        int rowi = b * 64 + (r - 1);           // cell row
        // stage 960 int4 of edge indices, pre-biased, as u16
        const v4i* ep4 = (const v4i*)(eidx + (size_t)rowi * 3840);
        for (int e = tid; e < 960; e += 512) {
            v4i q = __builtin_nontemporal_load(ep4 + e);
            int p0 = (e % 15) * 4;             // p of first component
            v4h sv;
            sv.x = (u16)(q.x + ((p0 + 0) / 3) * NV);
            sv.y = (u16)(q.y + ((p0 + 1) / 3) * NV);
            sv.z = (u16)(q.z + ((p0 + 2) / 3) * NV);
            sv.w = (u16)(q.w + ((p0 + 3) / 3) * NV);
            *(v4h*)(sidx + 4 * e) = sv;
        }
        if (tid < NH) comb[tid * 65] = tokw[tid];   // token col 0
        __syncthreads();

        int g = tid >> 3, l = tid & 7;         // cell, head-quad
        const u16* mi = sidx + g * 60;
        const char* Tb = (const char*)Tw + l * 8;
        f32x2 accA = {0.f, 0.f}, accB = {0.f, 0.f};
#pragma unroll
        for (int t = 0; t < 15; ++t) {         // 4 lookups per batch
            v4h q = *(const v4h*)(mi + 4 * t); // one ds_read_b64
#pragma unroll
            for (int c = 0; c < 4; ++c) {
                u32 idx = (c == 0) ? q.x : (c == 1) ? q.y : (c == 2) ? q.z : q.w;
                u32x2 u = *(const u32x2*)(Tb + ((size_t)idx << 6));
                f32x2 vA = { asf(u.x << 16), asf(u.x & 0xffff0000u) };
                f32x2 vB = { asf(u.y << 16), asf(u.y & 0xffff0000u) };
                accA += vA;                    // v_pk_add_f32
                accB += vB;
            }
        }

        int s  = spos[rowi * 64 + g];
        int sp = (s == 0) ? 1 : s;
        sp = (sp > 1) ? sp - 1 : sp;
        sp = (sp > ND) ? ND : sp;
        float m   = mask2d[b];
        float esc = m / (3.0f * (float)sp);
        v4f spv = ((const v4f*)(spw + s * NH))[l];   // heads 4l..4l+3
        comb[(4 * l + 0) * 65 + g + 1] = spv.x * m + accA.x * esc;
        comb[(4 * l + 1) * 65 + g + 1] = spv.y * m + accA.y * esc;
        comb[(4 * l + 2) * 65 + g + 1] = spv.z * m + accB.x * esc;
        comb[(4 * l + 3) * 65 + g + 1] = spv.w * m + accB.y * esc;
        __syncthreads();

        // write 32 heads x 65 j: full 260B rows, nontemporal
        for (int idx = tid; idx < NH * 65; idx += 512) {
            int h = idx / 65, j = idx - h * 65;
            __builtin_nontemporal_store(2.0f * abrow[j] + comb[idx],
                &out[(((size_t)b * NH + h) * 65 + r) * 65 + j]);
        }
    } else {
        __syncthreads();
        for (int idx = tid; idx < NH * 65; idx += 512) {
            int h = idx / 65, j = idx - h * 65;
            __builtin_nontemporal_store(2.0f * abrow[j] + tokw[h],
                &out[(((size_t)b * NH + h) * 65 + 0) * 65 + j]);
        }
    }
}

extern "C" void kernel_launch(void* const* d_in, const int* in_sizes, int n_in,
                              void* d_out, int out_size, void* d_ws, size_t ws_size,
                              hipStream_t stream) {
    const float* attn_bias   = (const float*)d_in[0];
    const int*   spatial_pos = (const int*)  d_in[1];
    // d_in[2] = x (unused), d_in[4] = attn_edge_type (unused)
    const int*   edge_input  = (const int*)  d_in[3];
    const float* mask_2d     = (const float*)d_in[5];
    const float* edge_enc_w  = (const float*)d_in[6];
    const float* edge_dis_w  = (const float*)d_in[7];
    const float* spatial_w   = (const float*)d_in[8];
    const float* token_w     = (const float*)d_in[9];
    float* out = (float*)d_out;
    __hip_bfloat16* T = (__hip_bfloat16*)d_ws;  // 1,967,360 B

    // Kernel 1: build T (bf16)
    prep_kernel<<<TBLOCKS, 256, 0, stream>>>(edge_enc_w, edge_dis_w, T);
    // Kernel 2: everything else, one block per output row
    main_kernel<<<NB * 65, 512, 0, stream>>>(attn_bias, spatial_pos, edge_input,
                                             mask_2d, spatial_w, token_w,
                                             (const u32*)T, out);
}

// Round 6
// 40.123 us; speedup vs baseline: 1.0057x; 1.0057x over previous
//
#include <hip/hip_runtime.h>
#include <hip/hip_bf16.h>

#define NH 32          // heads
#define NV 1537        // edge_enc_w rows
#define ND 20          // MULTI_HOP_MAX_DIST
#define NB 16          // batch
#define NN 64          // nodes

#define TROWS (ND*NV)                    // 30740
#define TBLOCKS ((TROWS + 7) / 8)        // 3843

typedef unsigned int   u32;
typedef unsigned short u16;
typedef __attribute__((ext_vector_type(2))) unsigned int   u32x2;
typedef __attribute__((ext_vector_type(2))) float          f32x2;
typedef __attribute__((ext_vector_type(4))) int            v4i;
typedef __attribute__((ext_vector_type(4))) float          v4f;
typedef __attribute__((ext_vector_type(4))) unsigned short v4h;

__device__ __forceinline__ float asf(u32 u) { return __uint_as_float(u); }

// ---------------- Kernel 1: T[d][v][h] = sum_k enc[v][k] * Wd[d][k][h], bf16 ----------
__global__ void __launch_bounds__(256)
prep_kernel(const float* __restrict__ enc,     // (1537,32)
            const float* __restrict__ wdis,    // (20,32,32)
            __hip_bfloat16* __restrict__ T) {  // (20,1537,32) out
    int row = blockIdx.x * 8 + (threadIdx.x >> 5);
    int h   = threadIdx.x & 31;
    if (row >= TROWS) return;
    int d = row / NV, v = row - d * NV;
    const float4* e4 = (const float4*)(enc + v * NH);
    const float*  w  = wdis + d * NH * NH + h;
    float acc = 0.f;
#pragma unroll
    for (int k4 = 0; k4 < 8; ++k4) {
        float4 e = e4[k4];
        acc += e.x * w[(k4 * 4 + 0) * NH];
        acc += e.y * w[(k4 * 4 + 1) * NH];
        acc += e.z * w[(k4 * 4 + 2) * NH];
        acc += e.w * w[(k4 * 4 + 3) * NH];
    }
    T[row * NH + h] = __float2bfloat16(acc);
}

// ---------------- Kernel 2: one block per (b, out-row r), 512 threads ----------------
// r==0: token row.  r>=1: 64 interior cells (i=r-1, j=0..63) -> out cols 1..64,
// token col 0. Gather: 8 lanes/cell, lane l = head-quad, u16 pre-biased indices.
__global__ void __launch_bounds__(512, 6)
main_kernel(const float* __restrict__ ab,      // (B,65,65)
            const int*   __restrict__ spos,    // (B,64,64)
            const int*   __restrict__ eidx,    // (B,64,64,20,3)
            const float* __restrict__ mask2d,  // (B,)
            const float* __restrict__ spw,     // (512,32)
            const float* __restrict__ tokw,    // (32,)
            const u32*   __restrict__ Tw,      // T rows: 16 uints (bf16x2)
            float*       __restrict__ out) {   // (B,32,65,65)
    __shared__ u16   sidx[64 * 60];            // 7680 B, pre-biased d*NV+idx
    __shared__ float comb[NH * 65];            // 8320 B, [h][out-j]
    __shared__ float abrow[65];

    int tid = threadIdx.x;
    int blk = blockIdx.x;                      // b*65 + r
    int b = blk / 65, r = blk - b * 65;

    if (tid < 65) abrow[tid] = ab[(b * 65 + r) * 65 + tid];

    if (r > 0) {
        int rowi = b * 64 + (r - 1);           // cell row
        // stage 960 int4 of edge indices, pre-biased, as u16
        const v4i* ep4 = (const v4i*)(eidx + (size_t)rowi * 3840);
        for (int e = tid; e < 960; e += 512) {
            v4i q = __builtin_nontemporal_load(ep4 + e);
            int p0 = (e % 15) * 4;             // p of first component
            v4h sv;
            sv.x = (u16)(q.x + ((p0 + 0) / 3) * NV);
            sv.y = (u16)(q.y + ((p0 + 1) / 3) * NV);
            sv.z = (u16)(q.z + ((p0 + 2) / 3) * NV);
            sv.w = (u16)(q.w + ((p0 + 3) / 3) * NV);
            *(v4h*)(sidx + 4 * e) = sv;
        }
        if (tid < NH) comb[tid * 65] = tokw[tid];   // token col 0
        __syncthreads();

        int g = tid >> 3, l = tid & 7;         // cell, head-quad
        const u16* mi = sidx + g * 60;
        const char* Tb = (const char*)Tw + l * 8;
        f32x2 accA = {0.f, 0.f}, accB = {0.f, 0.f};
#pragma unroll
        for (int t = 0; t < 15; ++t) {         // 4 lookups per batch
            v4h q = *(const v4h*)(mi + 4 * t); // one ds_read_b64
#pragma unroll
            for (int c = 0; c < 4; ++c) {
                u32 idx = (c == 0) ? q.x : (c == 1) ? q.y : (c == 2) ? q.z : q.w;
                u32x2 u = *(const u32x2*)(Tb + ((size_t)idx << 6));
                f32x2 vA = { asf(u.x << 16), asf(u.x & 0xffff0000u) };
                f32x2 vB = { asf(u.y << 16), asf(u.y & 0xffff0000u) };
                accA += vA;                    // v_pk_add_f32
                accB += vB;
            }
        }

        int s  = spos[rowi * 64 + g];
        int sp = (s == 0) ? 1 : s;
        sp = (sp > 1) ? sp - 1 : sp;
        sp = (sp > ND) ? ND : sp;
        float m   = mask2d[b];
        float esc = m / (3.0f * (float)sp);
        v4f spv = ((const v4f*)(spw + s * NH))[l];   // heads 4l..4l+3
        comb[(4 * l + 0) * 65 + g + 1] = spv.x * m + accA.x * esc;
        comb[(4 * l + 1) * 65 + g + 1] = spv.y * m + accA.y * esc;
        comb[(4 * l + 2) * 65 + g + 1] = spv.z * m + accB.x * esc;
        comb[(4 * l + 3) * 65 + g + 1] = spv.w * m + accB.y * esc;
        __syncthreads();

        // write 32 heads x 65 j: full 260B rows, nontemporal
        for (int idx = tid; idx < NH * 65; idx += 512) {
            int h = idx / 65, j = idx - h * 65;
            __builtin_nontemporal_store(2.0f * abrow[j] + comb[idx],
                &out[(((size_t)b * NH + h) * 65 + r) * 65 + j]);
        }
    } else {
        __syncthreads();
        for (int idx = tid; idx < NH * 65; idx += 512) {
            int h = idx / 65, j = idx - h * 65;
            __builtin_nontemporal_store(2.0f * abrow[j] + tokw[h],
                &out[(((size_t)b * NH + h) * 65 + 0) * 65 + j]);
        }
    }
}

extern "C" void kernel_launch(void* const* d_in, const int* in_sizes, int n_in,
                              void* d_out, int out_size, void* d_ws, size_t ws_size,
                              hipStream_t stream) {
    const float* attn_bias   = (const float*)d_in[0];
    const int*   spatial_pos = (const int*)  d_in[1];
    // d_in[2] = x (unused), d_in[4] = attn_edge_type (unused)
    const int*   edge_input  = (const int*)  d_in[3];
    const float* mask_2d     = (const float*)d_in[5];
    const float* edge_enc_w  = (const float*)d_in[6];
    const float* edge_dis_w  = (const float*)d_in[7];
    const float* spatial_w   = (const float*)d_in[8];
    const float* token_w     = (const float*)d_in[9];
    float* out = (float*)d_out;
    __hip_bfloat16* T = (__hip_bfloat16*)d_ws;  // 1,967,360 B

    // Kernel 1: build T (bf16)
    prep_kernel<<<TBLOCKS, 256, 0, stream>>>(edge_enc_w, edge_dis_w, T);
    // Kernel 2: everything else, one block per output row
    main_kernel<<<NB * 65, 512, 0, stream>>>(attn_bias, spatial_pos, edge_input,
                                             mask_2d, spatial_w, token_w,
                                             (const u32*)T, out);
}

// Round 7
// 30.575 us; speedup vs baseline: 1.3197x; 1.3123x over previous
//
#include <hip/hip_runtime.h>
#include <hip/hip_bf16.h>

#define NH 32          // heads
#define NV 1537        // edge_enc_w rows
#define ND 20          // MULTI_HOP_MAX_DIST
#define NB 16          // batch
#define NN 64          // nodes

#define TROWS (ND*NV)                    // 30740
#define TBLOCKS ((TROWS + 31) / 32)      // 961  (32 rows per block)
#define BORDER_N (NB*NH*65 + NB*NH*64)   // 66048
#define BBLOCKS ((BORDER_N + 255) / 256) // 258

typedef unsigned int u32;
typedef __attribute__((ext_vector_type(2))) float f32x2;
typedef __attribute__((ext_vector_type(4))) int   v4i;
typedef __attribute__((ext_vector_type(4))) float v4f;

// ---- fp8 e4m3 helpers (HW cvt; asm fallback keeps the same semantics) ----
__device__ __forceinline__ f32x2 fp8x2_to_f32(u32 u) {
#if __has_builtin(__builtin_amdgcn_cvt_pk_f32_fp8)
    return __builtin_amdgcn_cvt_pk_f32_fp8(u, false);   // decodes bytes 0,1
#else
    f32x2 r;
    asm("v_cvt_pk_f32_fp8 %0, %1" : "=v"(r) : "v"(u));
    return r;
#endif
}
__device__ __forceinline__ u32 f32x4_to_fp8(float a0, float a1, float a2, float a3) {
#if __has_builtin(__builtin_amdgcn_cvt_pk_fp8_f32)
    u32 u = __builtin_amdgcn_cvt_pk_fp8_f32(a0, a1, 0u, false);
    u     = __builtin_amdgcn_cvt_pk_fp8_f32(a2, a3, u,  true);
    return u;
#else
    u32 lo, hi;
    asm("v_cvt_pk_fp8_f32 %0, %1, %2" : "=v"(lo) : "v"(a0), "v"(a1));
    asm("v_cvt_pk_fp8_f32 %0, %1, %2" : "=v"(hi) : "v"(a2), "v"(a3));
    return (lo & 0xffffu) | (hi << 16);
#endif
}

// ---------------- Kernel 1: build T (fp8 e4m3, x256) + borders, fused ----------------
// T row = 32 heads x 1B = 32B = 8 u32. 8 lanes per row, lane l packs heads 4l..4l+3.
__global__ void __launch_bounds__(256)
prep_kernel(const float* __restrict__ enc,     // (1537,32)
            const float* __restrict__ wdis,    // (20,32,32)
            const float* __restrict__ ab,      // (B,65,65)
            const float* __restrict__ tokw,    // (32,)
            u32* __restrict__ T8,              // (30740, 8) u32 out
            float* __restrict__ out) {         // (B,32,65,65)
    int blk = blockIdx.x;
    if (blk < TBLOCKS) {
        int row = blk * 32 + (threadIdx.x >> 3);
        int l   = threadIdx.x & 7;
        if (row >= TROWS) return;
        int d = row / NV, v = row - d * NV;
        const float* e = enc + v * NH;
        const float* w = wdis + d * NH * NH + 4 * l;
        float a0 = 0.f, a1 = 0.f, a2 = 0.f, a3 = 0.f;
#pragma unroll
        for (int k = 0; k < NH; ++k) {
            float ev = e[k];                       // broadcast within row-group
            float4 w4 = *(const float4*)(w + k * NH);  // 8 lanes x 16B = 128B
            a0 += ev * w4.x; a1 += ev * w4.y;
            a2 += ev * w4.z; a3 += ev * w4.w;
        }
        T8[row * 8 + l] = f32x4_to_fp8(a0 * 256.f, a1 * 256.f,
                                       a2 * 256.f, a3 * 256.f);
    } else {
        int t = (blk - TBLOCKS) * 256 + threadIdx.x;
        const int nA = NB * NH * 65;   // row 0, all j
        if (t < nA) {
            int j = t % 65; int bh = t / 65; int h = bh & 31; int b = bh >> 5;
            __builtin_nontemporal_store(2.0f * ab[b * 4225 + j] + tokw[h],
                &out[((size_t)(b * NH + h) * 65 + 0) * 65 + j]);
        } else {
            t -= nA;                   // col 0, i >= 1
            if (t >= NB * NH * 64) return;
            int i = (t % 64) + 1; int bh = t / 64; int h = bh & 31; int b = bh >> 5;
            __builtin_nontemporal_store(2.0f * ab[b * 4225 + i * 65] + tokw[h],
                &out[((size_t)(b * NH + h) * 65 + i) * 65 + 0]);
        }
    }
}

// ---------------- Kernel 2: interior, half-row blocks (R4 structure) ----------------
// block = (b, i, half): 32 cells x 32 heads, 256 threads.
// group = 8 lanes = 1 cell; lane l covers heads {4l..4l+3} via one u32 (fp8x4)
// per gather -> full 32B T-row per 8-lane group.
__global__ void __launch_bounds__(256, 4)
main_kernel(const float* __restrict__ ab,          // (B,65,65)
            const int*   __restrict__ spos,        // (B,64,64)
            const int*   __restrict__ eidx,        // (B,64,64,20,3)
            const float* __restrict__ mask2d,      // (B,)
            const float* __restrict__ spw,         // (512,32)
            const u32*   __restrict__ Tw,          // T rows as 8x u32 (fp8)
            float*       __restrict__ out) {       // (B,32,65,65)
    __shared__ __align__(16) int sidx[32 * 60];    // 7680 B
    __shared__ float comb[32 * 33];                // [h][j] padded, 4224 B

    int tid  = threadIdx.x;
    int blk  = blockIdx.x;              // 0..2047
    int half = blk & 1;
    int bi   = blk >> 1;                // b*64 + i
    int b = bi >> 6, i = bi & 63;
    int j0 = half * 32;

    // stage 32 cells x 60 indices = 480 int4, nontemporal (protect T in L2)
    const v4i* ep4 = (const v4i*)(eidx + (size_t)(bi * 64 + j0) * 60);
    v4i* s4 = (v4i*)sidx;
    s4[tid] = __builtin_nontemporal_load(ep4 + tid);
    if (tid < 224) s4[256 + tid] = __builtin_nontemporal_load(ep4 + 256 + tid);
    __syncthreads();

    int g = tid >> 3, l = tid & 7;      // cell jj = g, lane = head-quad
    const int* mi = sidx + g * 60;
    const u32* Tl = Tw + l;             // per-lane u32 column; row stride 8

    f32x2 accA = {0.f, 0.f}, accB = {0.f, 0.f};
#pragma unroll
    for (int p = 0; p < 60; ++p) {
        int d = p / 3;                  // compile-time per unrolled iter
        u32 u = Tl[(size_t)(d * NV + mi[p]) * 8];
        accA += fp8x2_to_f32(u);        // heads 4l, 4l+1
        accB += fp8x2_to_f32(u >> 16);  // heads 4l+2, 4l+3
    }

    int s  = spos[bi * 64 + j0 + g];
    int sp = (s == 0) ? 1 : s;
    sp = (sp > 1) ? sp - 1 : sp;
    sp = (sp > ND) ? ND : sp;
    float m   = mask2d[b];
    float esc = m / (768.0f * (float)sp);          // /3sp and /256 fp8 scale
    v4f spv = ((const v4f*)(spw + s * NH))[l];     // heads 4l..4l+3, 16B/lane
    comb[(4 * l + 0) * 33 + g] = spv.x * m + accA.x * esc;
    comb[(4 * l + 1) * 33 + g] = spv.y * m + accA.y * esc;
    comb[(4 * l + 2) * 33 + g] = spv.z * m + accB.x * esc;
    comb[(4 * l + 3) * 33 + g] = spv.w * m + accB.y * esc;
    __syncthreads();

    // write phase: 32 consecutive j per 32-lane half-wave -> 128B segments
    int jw = tid & 31, hh = tid >> 5;   // hh in 0..7
    float a2b = 2.0f * ab[(b * 65 + i + 1) * 65 + (j0 + jw + 1)];
#pragma unroll
    for (int p = 0; p < 4; ++p) {
        int h = p * 8 + hh;
        __builtin_nontemporal_store(a2b + comb[h * 33 + jw],
            &out[((size_t)(b * NH + h) * 65 + i + 1) * 65 + (j0 + jw + 1)]);
    }
}

extern "C" void kernel_launch(void* const* d_in, const int* in_sizes, int n_in,
                              void* d_out, int out_size, void* d_ws, size_t ws_size,
                              hipStream_t stream) {
    const float* attn_bias   = (const float*)d_in[0];
    const int*   spatial_pos = (const int*)  d_in[1];
    // d_in[2] = x (unused), d_in[4] = attn_edge_type (unused)
    const int*   edge_input  = (const int*)  d_in[3];
    const float* mask_2d     = (const float*)d_in[5];
    const float* edge_enc_w  = (const float*)d_in[6];
    const float* edge_dis_w  = (const float*)d_in[7];
    const float* spatial_w   = (const float*)d_in[8];
    const float* token_w     = (const float*)d_in[9];
    float* out = (float*)d_out;
    u32* T8 = (u32*)d_ws;   // 30740 * 32B = 983,680 B

    // Kernel 1: build T (fp8) + borders
    prep_kernel<<<TBLOCKS + BBLOCKS, 256, 0, stream>>>(edge_enc_w, edge_dis_w,
                                                       attn_bias, token_w, T8, out);
    // Kernel 2: interior (half-row blocks, 8-lane groups)
    main_kernel<<<NB * NN * 2, 256, 0, stream>>>(attn_bias, spatial_pos, edge_input,
                                                 mask_2d, spatial_w, T8, out);
}